// Round 14
// baseline (292.647 us; speedup 1.0000x reference)
//
#include <hip/hip_runtime.h>

#define N_NODES 50000
#define N_EDGES 800000
#define NUM_GRAPHS 16
#define NUM_CLASSES 247
#define SCAN_BLOCKS ((N_NODES + 255) / 256)  // 196

typedef __attribute__((ext_vector_type(8))) short bf16x8;
typedef __attribute__((ext_vector_type(4))) float f32x4;

static inline int nblk(long n) { return (int)((n + 255) / 256); }

__device__ __forceinline__ float bfl(unsigned short u) {
    return __uint_as_float((unsigned)u << 16);
}
__device__ __forceinline__ float bflo(unsigned u) {
    return __uint_as_float(u << 16);
}
__device__ __forceinline__ float bfhi(unsigned u) {
    return __uint_as_float(u & 0xFFFF0000u);
}
__device__ __forceinline__ unsigned short bf16_rne(float f) {
    unsigned u = __float_as_uint(f);
    u += 0x7FFF + ((u >> 16) & 1);
    return (unsigned short)(u >> 16);
}

// ---- degree histogram; atomic return value = edge rank within dst ----------
__global__ void k_deg(const int* __restrict__ col, int* __restrict__ degi,
                      int* __restrict__ pos, int E) {
    int e = blockIdx.x * blockDim.x + threadIdx.x;
    if (e < E) pos[e] = atomicAdd(&degi[col[e]], 1);
}

// ---- scan phase 1: per-block exclusive scan + block sums + batch histogram -
__global__ __launch_bounds__(256) void k_scan1(const int* __restrict__ degi,
                                               int* __restrict__ rowptr,
                                               int* __restrict__ bsum,
                                               const int* __restrict__ batch,
                                               float* __restrict__ pcnt, int N) {
    __shared__ int buf[256];
    __shared__ int hist[NUM_GRAPHS];
    int t = threadIdx.x;
    if (t < NUM_GRAPHS) hist[t] = 0;
    int i = blockIdx.x * 256 + t;
    int v = (i < N) ? degi[i] : 0;
    buf[t] = v;
    if (i < N) atomicAdd(&hist[batch[i]], 1);
    __syncthreads();
#pragma unroll
    for (int off = 1; off < 256; off <<= 1) {
        int tmp = (t >= off) ? buf[t - off] : 0;
        __syncthreads();
        if (t >= off) buf[t] += tmp;
        __syncthreads();
    }
    if (i < N) rowptr[i] = buf[t] - v;  // exclusive within block
    if (t == 255) bsum[blockIdx.x] = buf[255];
    if (t < NUM_GRAPHS && hist[t] > 0) atomicAdd(&pcnt[t], (float)hist[t]);
}

// ---- scan phase 2 (folded) + dinv + pre-scaled xs + weight casts -----------
__global__ __launch_bounds__(256) void k_scan3(int* __restrict__ rowptr,
                                               const int* __restrict__ bsum,
                                               const int* __restrict__ degi,
                                               float* __restrict__ dinv,
                                               const float* __restrict__ x,
                                               float* __restrict__ xs,
                                               const float* __restrict__ W2,
                                               const float* __restrict__ W3,
                                               unsigned short* __restrict__ Wt2,
                                               unsigned short* __restrict__ Wt3,
                                               int N) {
    __shared__ int red[256];
    int t = threadIdx.x;
    int b = blockIdx.x;
    red[t] = (t < b) ? bsum[t] : 0;  // b <= 195 < 256
    __syncthreads();
#pragma unroll
    for (int off = 128; off > 0; off >>= 1) {
        if (t < off) red[t] += red[t + off];
        __syncthreads();
    }
    int boff = red[0];
    int i = b * 256 + t;
    if (i < N) {
        rowptr[i] += boff;
        float dv = rsqrtf((float)degi[i] + 1.0f);  // +1 = self loop
        dinv[i] = dv;
        xs[i * 3 + 0] = dv * x[i * 3 + 0];
        xs[i * 3 + 1] = dv * x[i * 3 + 1];
        xs[i * 3 + 2] = dv * x[i * 3 + 2];
    }
    if (i == 0) rowptr[N] = N_EDGES;
    // folded weight cast+transpose (40960 items over 50176 threads)
    if (i < 64 * 128) {                       // Wt2: [f=128][k=64]
        int f = i / 64, k = i % 64;
        Wt2[i] = bf16_rne(W2[k * 128 + f]);
    } else if (i < 64 * 128 + 128 * 256) {    // Wt3: [f=256][k=128]
        int j = i - 64 * 128;
        int f = j / 128, k = j % 128;
        Wt3[j] = bf16_rne(W3[k * 256 + f]);
    }
}

// ---- CSR fill: no atomic (rank precomputed) --------------------------------
__global__ void k_fill(const int* __restrict__ row, const int* __restrict__ col,
                       const int* __restrict__ rowptr, const int* __restrict__ pos,
                       int* __restrict__ csr_src, int E) {
    int e = blockIdx.x * blockDim.x + threadIdx.x;
    if (e >= E) return;
    int c = col[e];
    csr_src[rowptr[c] + pos[e]] = row[e];
}

// ---- fused layer 1: p1 = dv*(xs[v]+Σxs[r]); h1' = dv*relu(p1 W1 + b1) ------
__global__ void k_layer1(const float* __restrict__ xs, const float* __restrict__ dinv,
                         const int* __restrict__ rowptr, const int* __restrict__ csr_src,
                         const float* __restrict__ W1, const float* __restrict__ b1,
                         unsigned short* __restrict__ out, int N) {
    int v = blockIdx.x * blockDim.x + threadIdx.x;
    if (v >= N) return;
    float a0 = xs[v * 3 + 0];
    float a1 = xs[v * 3 + 1];
    float a2 = xs[v * 3 + 2];
    int j1 = rowptr[v + 1];
    for (int j = rowptr[v]; j < j1; ++j) {
        int r = csr_src[j];
        a0 += xs[r * 3 + 0];
        a1 += xs[r * 3 + 1];
        a2 += xs[r * 3 + 2];
    }
    float dv = dinv[v];
    float p0 = dv * a0, p1 = dv * a1, p2 = dv * a2;
    unsigned short* ov = out + (long)v * 64;
#pragma unroll
    for (int f = 0; f < 64; f += 2) {
        float s0 = fmaf(p0, W1[f],     fmaf(p1, W1[64 + f],     fmaf(p2, W1[128 + f],     b1[f])));
        float s1 = fmaf(p0, W1[f + 1], fmaf(p1, W1[64 + f + 1], fmaf(p2, W1[128 + f + 1], b1[f + 1])));
        s0 = fmaxf(s0, 0.0f) * dv;  // pre-scale for next prop
        s1 = fmaxf(s1, 0.0f) * dv;
        unsigned pk = (unsigned)bf16_rne(s0) | ((unsigned)bf16_rne(s1) << 16);
        *(unsigned*)(ov + f) = pk;
    }
}

// ---- FUSED prop + MFMA GEMM per 16-row m-tile, MULTI-EDGE GATHER -----------
// R13 evidence: gather is request-rate bound (bf16 halved bytes vs fp32 with
// no time change — same instruction count). Fix: split the wave across edges.
// 4 features/lane (8 B dwordx2) -> LPR=K/4 lanes cover a row -> G=64/LPR edges
// per load instruction (K=128: G=2; K=64: G=4, replacing 2 B u16 loads).
// Group partials merged by shfl_xor tree; self term post-reduce; group 0
// writes the 8 B LDS chunk. Phase 2 = verified R9/R11 MFMA layout, unchanged.
template <int K, int F, bool PRESCALE>
__global__ __launch_bounds__(256) void k_fused(
        const unsigned short* __restrict__ h, const float* __restrict__ dinv,
        const int* __restrict__ rowptr, const int* __restrict__ csr_src,
        const unsigned short* __restrict__ Wt, const float* __restrict__ b,
        unsigned short* __restrict__ out, int N) {
    constexpr int NF = F / 16;    // f-tiles: 8 (F=128) / 16 (F=256)
    constexpr int FPW = NF / 4;   // f-tiles per wave: 2 / 4
    constexpr int KB = K / 32;    // k-blocks: 2 / 4
    constexpr int LPR = K / 4;    // lanes per row: 32 / 16
    constexpr int G = 64 / LPR;   // edges per load instr: 2 / 4
    constexpr int PADK = K + 8;
    __shared__ unsigned short plds[16][PADK];
    int wave = threadIdx.x >> 6;
    int lane = threadIdx.x & 63;
    int m0 = blockIdx.x * 16;
    int grp = lane / LPR;         // 0..G-1 (edge subset)
    int li = lane % LPR;          // lane within row; features 4*li..4*li+3

    // ---- phase 1: propagation into LDS ----
    for (int rr = 0; rr < 4; ++rr) {
        int v = m0 + wave * 4 + rr;
        float a0 = 0.f, a1 = 0.f, a2 = 0.f, a3 = 0.f;
        int j0 = __builtin_amdgcn_readfirstlane(rowptr[v]);
        int j1 = __builtin_amdgcn_readfirstlane(rowptr[v + 1]);
        int j = j0;
        // main: 4 edges per group per iter = 4*G edges, 4 dwordx2 in flight
        for (; j + 4 * G <= j1; j += 4 * G) {
            int r[4];
#pragma unroll
            for (int u = 0; u < 4; ++u) r[u] = csr_src[j + grp * 4 + u];
            uint2 t[4];
#pragma unroll
            for (int u = 0; u < 4; ++u)
                t[u] = *(const uint2*)(h + (long)r[u] * K + li * 4);
#pragma unroll
            for (int u = 0; u < 4; ++u) {
                a0 += bflo(t[u].x); a1 += bfhi(t[u].x);
                a2 += bflo(t[u].y); a3 += bfhi(t[u].y);
            }
        }
        // G edges per iteration
        for (; j + G <= j1; j += G) {
            int r = csr_src[j + grp];
            uint2 t = *(const uint2*)(h + (long)r * K + li * 4);
            a0 += bflo(t.x); a1 += bfhi(t.x);
            a2 += bflo(t.y); a3 += bfhi(t.y);
        }
        // sub-G tail (0..G-1 edges): group grp handles edge j+grp if valid
        int rem = j1 - j;
        if (grp < rem) {
            int r = csr_src[j + grp];
            uint2 t = *(const uint2*)(h + (long)r * K + li * 4);
            a0 += bflo(t.x); a1 += bfhi(t.x);
            a2 += bflo(t.y); a3 += bfhi(t.y);
        }
        // merge group partials (tree over lanes li, li+LPR, ...)
#pragma unroll
        for (int off = LPR; off < 64; off <<= 1) {
            a0 += __shfl_xor(a0, off);
            a1 += __shfl_xor(a1, off);
            a2 += __shfl_xor(a2, off);
            a3 += __shfl_xor(a3, off);
        }
        // self term (pre-scaled input), then scale by dv
        uint2 s = *(const uint2*)(h + (long)v * K + li * 4);
        a0 += bflo(s.x); a1 += bfhi(s.x);
        a2 += bflo(s.y); a3 += bfhi(s.y);
        float dv = dinv[v];
        if (grp == 0) {
            unsigned p0 = (unsigned)bf16_rne(dv * a0) | ((unsigned)bf16_rne(dv * a1) << 16);
            unsigned p1 = (unsigned)bf16_rne(dv * a2) | ((unsigned)bf16_rne(dv * a3) << 16);
            uint2 pk = {p0, p1};
            *(uint2*)&plds[wave * 4 + rr][li * 4] = pk;
        }
    }
    __syncthreads();

    // ---- phase 2: MFMA (layout verified R9/R11) ----
    int quad = lane >> 4;
    int l16 = lane & 15;
    bf16x8 afr[KB];
#pragma unroll
    for (int kb = 0; kb < KB; ++kb)
        afr[kb] = *(const bf16x8*)(const void*)&plds[l16][kb * 32 + quad * 8];
#pragma unroll
    for (int fi = 0; fi < FPW; ++fi) {
        int f0 = (wave * FPW + fi) * 16;
        const unsigned short* wrow = Wt + (long)(f0 + l16) * K + quad * 8;
        f32x4 acc4 = {0.f, 0.f, 0.f, 0.f};
#pragma unroll
        for (int kb = 0; kb < KB; ++kb) {
            bf16x8 bb = *(const bf16x8*)(const void*)(wrow + kb * 32);
            acc4 = __builtin_amdgcn_mfma_f32_16x16x32_bf16(afr[kb], bb, acc4, 0, 0, 0);
        }
        float bias = b[f0 + l16];
#pragma unroll
        for (int r = 0; r < 4; ++r) {
            int m = m0 + quad * 4 + r;
            float val = fmaxf(acc4[r] + bias, 0.0f);
            if (PRESCALE) val *= dinv[m];
            out[(long)m * F + f0 + l16] = bf16_rne(val);
        }
    }
}

// ---- pooling over bf16 h3: 64 nodes/block, register acc, flush on change ---
#define POOL_CHUNK 64
__global__ __launch_bounds__(256) void k_pool(
        const unsigned short* __restrict__ h, const int* __restrict__ batch,
        float* __restrict__ psum, int N) {
    int tid = threadIdx.x;  // feature
    int n0 = blockIdx.x * POOL_CHUNK;
    int n1 = n0 + POOL_CHUNK;
    if (n1 > N) n1 = N;
    int gcur = batch[n0];  // sorted -> uniform scalar
    float racc = 0.0f;
    for (int n = n0; n < n1; ++n) {
        int g = batch[n];
        if (g != gcur) {
            atomicAdd(&psum[gcur * 256 + tid], racc);
            racc = 0.0f;
            gcur = g;
        }
        racc += bfl(h[(long)n * 256 + tid]);
    }
    atomicAdd(&psum[gcur * 256 + tid], racc);
}

// ---- final FC --------------------------------------------------------------
__global__ void k_fc(const float* __restrict__ psum, const float* __restrict__ pcnt,
                     const float* __restrict__ Wfc, const float* __restrict__ bfc,
                     float* __restrict__ out) {
    int tid = blockIdx.x * blockDim.x + threadIdx.x;
    if (tid >= NUM_GRAPHS * NUM_CLASSES) return;
    int g = tid / NUM_CLASSES;
    int c = tid % NUM_CLASSES;
    float s = 0.0f;
#pragma unroll 8
    for (int k = 0; k < 256; ++k) s = fmaf(psum[g * 256 + k], Wfc[k * NUM_CLASSES + c], s);
    float cnt = pcnt[g];
    cnt = cnt > 1.0f ? cnt : 1.0f;
    out[tid] = s / cnt + bfc[c];
}

extern "C" void kernel_launch(void* const* d_in, const int* in_sizes, int n_in,
                              void* d_out, int out_size, void* d_ws, size_t ws_size,
                              hipStream_t stream) {
    const float* x     = (const float*)d_in[0];
    const int*   ei    = (const int*)d_in[1];
    const int*   batch = (const int*)d_in[2];
    const float* W1    = (const float*)d_in[3];
    const float* b1    = (const float*)d_in[4];
    const float* W2    = (const float*)d_in[5];
    const float* b2    = (const float*)d_in[6];
    const float* W3    = (const float*)d_in[7];
    const float* b3    = (const float*)d_in[8];
    const float* Wfc   = (const float*)d_in[9];
    const float* bfc   = (const float*)d_in[10];
    float* out = (float*)d_out;

    const int* row = ei;            // src
    const int* col = ei + N_EDGES;  // dst

    // workspace layout (~85 MB), bf16 arrays 16B-aligned
    float*  bufA = (float*)d_ws;                         // N*256 f32 (H3 bf16 lives here)
    float*  xs   = bufA + (size_t)N_NODES * 256;         // N*3 f32 (pre-scaled x)
    float*  dinv = xs + (size_t)N_NODES * 3;             // N
    float*  psum = dinv + N_NODES;                       // 16*256
    float*  pcnt = psum + NUM_GRAPHS * 256;              // 16
    unsigned short* X   = (unsigned short*)(pcnt + NUM_GRAPHS);  // N*128 bf16 (h1')
    unsigned short* Y   = X + (size_t)N_NODES * 128;             // N*128 bf16 (h2')
    unsigned short* Wt2 = Y + (size_t)N_NODES * 128;             // 128*64
    unsigned short* Wt3 = Wt2 + 128 * 64;                        // 256*128
    unsigned short* H3  = (unsigned short*)bufA;                 // N*256 bf16
    int* degi   = (int*)(Wt3 + 256 * 128);               // N
    int* rowptr = degi + N_NODES;                        // N+1
    int* csrsrc = rowptr + N_NODES + 1;                  // E
    int* pos    = csrsrc + N_EDGES;                      // E
    int* bsum   = pos + N_EDGES;                         // SCAN_BLOCKS

    hipMemsetAsync(degi, 0, N_NODES * sizeof(int), stream);
    hipMemsetAsync(psum, 0, (NUM_GRAPHS * 256 + NUM_GRAPHS) * sizeof(float), stream);

    // ---- CSR build + norms + pre-scaled x + weight casts ----
    k_deg<<<nblk(N_EDGES), 256, 0, stream>>>(col, degi, pos, N_EDGES);
    k_scan1<<<SCAN_BLOCKS, 256, 0, stream>>>(degi, rowptr, bsum, batch, pcnt, N_NODES);
    k_scan3<<<SCAN_BLOCKS, 256, 0, stream>>>(rowptr, bsum, degi, dinv, x, xs,
                                             W2, W3, Wt2, Wt3, N_NODES);
    k_fill<<<nblk(N_EDGES), 256, 0, stream>>>(row, col, rowptr, pos, csrsrc, N_EDGES);

    // ---- layer 1 (fused prop+linear): X = h1' = d*relu((A~x)W1+b1), bf16 ---
    k_layer1<<<nblk(N_NODES), 256, 0, stream>>>(xs, dinv, rowptr, csrsrc, W1, b1, X, N_NODES);

    int mtiles = N_NODES / 16;  // 3125, exact

    // ---- layer 2 fused: Y = h2' = d*relu((A~-apply X) W2 + b2) -------------
    k_fused<64, 128, true><<<mtiles, 256, 0, stream>>>(X, dinv, rowptr, csrsrc,
                                                       Wt2, b2, Y, N_NODES);

    // ---- layer 3 fused: H3 = h3 = relu((A~-apply Y) W3 + b3) (unscaled) ----
    k_fused<128, 256, false><<<mtiles, 256, 0, stream>>>(Y, dinv, rowptr, csrsrc,
                                                         Wt3, b3, H3, N_NODES);

    // ---- global mean pool + FC ----
    int pool_blocks = (N_NODES + POOL_CHUNK - 1) / POOL_CHUNK;
    k_pool<<<pool_blocks, 256, 0, stream>>>(H3, batch, psum, N_NODES);
    k_fc<<<nblk(NUM_GRAPHS * NUM_CLASSES), 256, 0, stream>>>(psum, pcnt, Wfc, bfc, out);
}

// Round 15
// 286.441 us; speedup vs baseline: 1.0217x; 1.0217x over previous
//
#include <hip/hip_runtime.h>

#define N_NODES 50000
#define N_EDGES 800000
#define NUM_GRAPHS 16
#define NUM_CLASSES 247
#define SCAN_BLOCKS ((N_NODES + 255) / 256)  // 196

typedef __attribute__((ext_vector_type(8))) short bf16x8;
typedef __attribute__((ext_vector_type(4))) float f32x4;

static inline int nblk(long n) { return (int)((n + 255) / 256); }

__device__ __forceinline__ float bfl(unsigned short u) {
    return __uint_as_float((unsigned)u << 16);
}
__device__ __forceinline__ unsigned short bf16_rne(float f) {
    unsigned u = __float_as_uint(f);
    u += 0x7FFF + ((u >> 16) & 1);
    return (unsigned short)(u >> 16);
}

// ---- degree histogram; atomic return value = edge rank within dst ----------
__global__ void k_deg(const int* __restrict__ col, int* __restrict__ degi,
                      int* __restrict__ pos, int E) {
    int e = blockIdx.x * blockDim.x + threadIdx.x;
    if (e < E) pos[e] = atomicAdd(&degi[col[e]], 1);
}

// ---- scan phase 1: per-block exclusive scan + block sums + batch histogram -
__global__ __launch_bounds__(256) void k_scan1(const int* __restrict__ degi,
                                               int* __restrict__ rowptr,
                                               int* __restrict__ bsum,
                                               const int* __restrict__ batch,
                                               float* __restrict__ pcnt, int N) {
    __shared__ int buf[256];
    __shared__ int hist[NUM_GRAPHS];
    int t = threadIdx.x;
    if (t < NUM_GRAPHS) hist[t] = 0;
    int i = blockIdx.x * 256 + t;
    int v = (i < N) ? degi[i] : 0;
    buf[t] = v;
    if (i < N) atomicAdd(&hist[batch[i]], 1);
    __syncthreads();
#pragma unroll
    for (int off = 1; off < 256; off <<= 1) {
        int tmp = (t >= off) ? buf[t - off] : 0;
        __syncthreads();
        if (t >= off) buf[t] += tmp;
        __syncthreads();
    }
    if (i < N) rowptr[i] = buf[t] - v;  // exclusive within block
    if (t == 255) bsum[blockIdx.x] = buf[255];
    if (t < NUM_GRAPHS && hist[t] > 0) atomicAdd(&pcnt[t], (float)hist[t]);
}

// ---- scan phase 2 (folded) + dinv + pre-scaled xs + weight casts -----------
__global__ __launch_bounds__(256) void k_scan3(int* __restrict__ rowptr,
                                               const int* __restrict__ bsum,
                                               const int* __restrict__ degi,
                                               float* __restrict__ dinv,
                                               const float* __restrict__ x,
                                               float* __restrict__ xs,
                                               const float* __restrict__ W2,
                                               const float* __restrict__ W3,
                                               unsigned short* __restrict__ Wt2,
                                               unsigned short* __restrict__ Wt3,
                                               int N) {
    __shared__ int red[256];
    int t = threadIdx.x;
    int b = blockIdx.x;
    red[t] = (t < b) ? bsum[t] : 0;  // b <= 195 < 256
    __syncthreads();
#pragma unroll
    for (int off = 128; off > 0; off >>= 1) {
        if (t < off) red[t] += red[t + off];
        __syncthreads();
    }
    int boff = red[0];
    int i = b * 256 + t;
    if (i < N) {
        rowptr[i] += boff;
        float dv = rsqrtf((float)degi[i] + 1.0f);  // +1 = self loop
        dinv[i] = dv;
        xs[i * 3 + 0] = dv * x[i * 3 + 0];
        xs[i * 3 + 1] = dv * x[i * 3 + 1];
        xs[i * 3 + 2] = dv * x[i * 3 + 2];
    }
    if (i == 0) rowptr[N] = N_EDGES;
    // folded weight cast+transpose (40960 items over 50176 threads)
    if (i < 64 * 128) {                       // Wt2: [f=128][k=64]
        int f = i / 64, k = i % 64;
        Wt2[i] = bf16_rne(W2[k * 128 + f]);
    } else if (i < 64 * 128 + 128 * 256) {    // Wt3: [f=256][k=128]
        int j = i - 64 * 128;
        int f = j / 128, k = j % 128;
        Wt3[j] = bf16_rne(W3[k * 256 + f]);
    }
}

// ---- CSR fill: no atomic (rank precomputed) --------------------------------
__global__ void k_fill(const int* __restrict__ row, const int* __restrict__ col,
                       const int* __restrict__ rowptr, const int* __restrict__ pos,
                       int* __restrict__ csr_src, int E) {
    int e = blockIdx.x * blockDim.x + threadIdx.x;
    if (e >= E) return;
    int c = col[e];
    csr_src[rowptr[c] + pos[e]] = row[e];
}

// ---- fused layer 1: p1 = dv*(xs[v]+Σxs[r]); h1' = dv*relu(p1 W1 + b1) ------
__global__ void k_layer1(const float* __restrict__ xs, const float* __restrict__ dinv,
                         const int* __restrict__ rowptr, const int* __restrict__ csr_src,
                         const float* __restrict__ W1, const float* __restrict__ b1,
                         unsigned short* __restrict__ out, int N) {
    int v = blockIdx.x * blockDim.x + threadIdx.x;
    if (v >= N) return;
    float a0 = xs[v * 3 + 0];
    float a1 = xs[v * 3 + 1];
    float a2 = xs[v * 3 + 2];
    int j1 = rowptr[v + 1];
    for (int j = rowptr[v]; j < j1; ++j) {
        int r = csr_src[j];
        a0 += xs[r * 3 + 0];
        a1 += xs[r * 3 + 1];
        a2 += xs[r * 3 + 2];
    }
    float dv = dinv[v];
    float p0 = dv * a0, p1 = dv * a1, p2 = dv * a2;
    unsigned short* ov = out + (long)v * 64;
#pragma unroll
    for (int f = 0; f < 64; f += 2) {
        float s0 = fmaf(p0, W1[f],     fmaf(p1, W1[64 + f],     fmaf(p2, W1[128 + f],     b1[f])));
        float s1 = fmaf(p0, W1[f + 1], fmaf(p1, W1[64 + f + 1], fmaf(p2, W1[128 + f + 1], b1[f + 1])));
        s0 = fmaxf(s0, 0.0f) * dv;  // pre-scale for next prop
        s1 = fmaxf(s1, 0.0f) * dv;
        unsigned pk = (unsigned)bf16_rne(s0) | ((unsigned)bf16_rne(s1) << 16);
        *(unsigned*)(ov + f) = pk;
    }
}

// ---- FUSED prop + MFMA GEMM per 16-row m-tile, 2-ROW INTERLEAVED GATHER ----
// R13 gather (wave-per-row, 8-edge unroll, 8 loads in flight) = 69 us.
// R14 (multi-edge split, 4 in flight) = 75 us -> MLP, not instruction count,
// is the lever. Here: two independent 8-edge streams per wave (rows va, vb)
// -> 16 outstanding loads, ZERO extra per-edge VALU. Per-row j-order summation
// unchanged -> bit-identical output (absmax must stay 4.882812e-4).
// Phase 2 = verified R9/R11 MFMA layout, unchanged.
template <int K, int F, bool PRESCALE>
__global__ __launch_bounds__(256) void k_fused(
        const unsigned short* __restrict__ h, const float* __restrict__ dinv,
        const int* __restrict__ rowptr, const int* __restrict__ csr_src,
        const unsigned short* __restrict__ Wt, const float* __restrict__ b,
        unsigned short* __restrict__ out, int N) {
    constexpr int NF = F / 16;    // f-tiles: 8 (F=128) / 16 (F=256)
    constexpr int FPW = NF / 4;   // f-tiles per wave: 2 / 4
    constexpr int KB = K / 32;    // k-blocks: 2 / 4
    constexpr int KL = K / 64;    // features per lane in prop: 1 / 2
    constexpr int PADK = K + 8;
    __shared__ unsigned short plds[16][PADK];
    int wave = threadIdx.x >> 6;
    int lane = threadIdx.x & 63;
    int m0 = blockIdx.x * 16;

    // ---- phase 1: propagation into LDS, rows processed in pairs ----
    for (int pr = 0; pr < 2; ++pr) {
        int va = m0 + wave * 4 + pr * 2;
        int vb = va + 1;
        float acca[KL], accb[KL];
        const unsigned short* hva = h + (long)va * K + lane * KL;
        const unsigned short* hvb = h + (long)vb * K + lane * KL;
        if (KL == 2) {
            unsigned ua = *(const unsigned*)hva;
            unsigned ub = *(const unsigned*)hvb;
            acca[0] = __uint_as_float(ua << 16);
            acca[1] = __uint_as_float(ua & 0xFFFF0000u);
            accb[0] = __uint_as_float(ub << 16);
            accb[1] = __uint_as_float(ub & 0xFFFF0000u);
        } else {
            acca[0] = bfl(hva[0]);
            accb[0] = bfl(hvb[0]);
        }
        int ja  = __builtin_amdgcn_readfirstlane(rowptr[va]);
        int j1a = __builtin_amdgcn_readfirstlane(rowptr[va + 1]);
        int jb  = j1a;  // rowptr[vb] == rowptr[va+1]
        int j1b = __builtin_amdgcn_readfirstlane(rowptr[vb + 1]);
        // paired main loop: 2 x 8 independent loads in flight
        while (ja + 8 <= j1a && jb + 8 <= j1b) {
            int ra[8], rb[8];
#pragma unroll
            for (int u = 0; u < 8; ++u) ra[u] = csr_src[ja + u];
#pragma unroll
            for (int u = 0; u < 8; ++u) rb[u] = csr_src[jb + u];
            if (KL == 2) {
                unsigned ta[8], tb[8];
#pragma unroll
                for (int u = 0; u < 8; ++u)
                    ta[u] = *(const unsigned*)(h + (long)ra[u] * K + lane * 2);
#pragma unroll
                for (int u = 0; u < 8; ++u)
                    tb[u] = *(const unsigned*)(h + (long)rb[u] * K + lane * 2);
#pragma unroll
                for (int u = 0; u < 8; ++u) {
                    acca[0] += __uint_as_float(ta[u] << 16);
                    acca[1] += __uint_as_float(ta[u] & 0xFFFF0000u);
                }
#pragma unroll
                for (int u = 0; u < 8; ++u) {
                    accb[0] += __uint_as_float(tb[u] << 16);
                    accb[1] += __uint_as_float(tb[u] & 0xFFFF0000u);
                }
            } else {
                unsigned short ta[8], tb[8];
#pragma unroll
                for (int u = 0; u < 8; ++u) ta[u] = h[(long)ra[u] * K + lane];
#pragma unroll
                for (int u = 0; u < 8; ++u) tb[u] = h[(long)rb[u] * K + lane];
#pragma unroll
                for (int u = 0; u < 8; ++u) acca[0] += bfl(ta[u]);
#pragma unroll
                for (int u = 0; u < 8; ++u) accb[0] += bfl(tb[u]);
            }
            ja += 8;
            jb += 8;
        }
        // drain row a (8-unroll then singles; same j-order)
        for (; ja + 8 <= j1a; ja += 8) {
            int r[8];
#pragma unroll
            for (int u = 0; u < 8; ++u) r[u] = csr_src[ja + u];
            if (KL == 2) {
                unsigned tv[8];
#pragma unroll
                for (int u = 0; u < 8; ++u)
                    tv[u] = *(const unsigned*)(h + (long)r[u] * K + lane * 2);
#pragma unroll
                for (int u = 0; u < 8; ++u) {
                    acca[0] += __uint_as_float(tv[u] << 16);
                    acca[1] += __uint_as_float(tv[u] & 0xFFFF0000u);
                }
            } else {
                unsigned short tv[8];
#pragma unroll
                for (int u = 0; u < 8; ++u) tv[u] = h[(long)r[u] * K + lane];
#pragma unroll
                for (int u = 0; u < 8; ++u) acca[0] += bfl(tv[u]);
            }
        }
        for (; ja < j1a; ++ja) {
            int r = csr_src[ja];
            if (KL == 2) {
                unsigned u = *(const unsigned*)(h + (long)r * K + lane * 2);
                acca[0] += __uint_as_float(u << 16);
                acca[1] += __uint_as_float(u & 0xFFFF0000u);
            } else {
                acca[0] += bfl(h[(long)r * K + lane]);
            }
        }
        // drain row b
        for (; jb + 8 <= j1b; jb += 8) {
            int r[8];
#pragma unroll
            for (int u = 0; u < 8; ++u) r[u] = csr_src[jb + u];
            if (KL == 2) {
                unsigned tv[8];
#pragma unroll
                for (int u = 0; u < 8; ++u)
                    tv[u] = *(const unsigned*)(h + (long)r[u] * K + lane * 2);
#pragma unroll
                for (int u = 0; u < 8; ++u) {
                    accb[0] += __uint_as_float(tv[u] << 16);
                    accb[1] += __uint_as_float(tv[u] & 0xFFFF0000u);
                }
            } else {
                unsigned short tv[8];
#pragma unroll
                for (int u = 0; u < 8; ++u) tv[u] = h[(long)r[u] * K + lane];
#pragma unroll
                for (int u = 0; u < 8; ++u) accb[0] += bfl(tv[u]);
            }
        }
        for (; jb < j1b; ++jb) {
            int r = csr_src[jb];
            if (KL == 2) {
                unsigned u = *(const unsigned*)(h + (long)r * K + lane * 2);
                accb[0] += __uint_as_float(u << 16);
                accb[1] += __uint_as_float(u & 0xFFFF0000u);
            } else {
                accb[0] += bfl(h[(long)r * K + lane]);
            }
        }
        float da = dinv[va];
        float db = dinv[vb];
        int rla = wave * 4 + pr * 2;
        if (KL == 2) {
            unsigned pa = (unsigned)bf16_rne(da * acca[0]) | ((unsigned)bf16_rne(da * acca[1]) << 16);
            unsigned pb = (unsigned)bf16_rne(db * accb[0]) | ((unsigned)bf16_rne(db * accb[1]) << 16);
            *(unsigned*)&plds[rla][lane * 2] = pa;
            *(unsigned*)&plds[rla + 1][lane * 2] = pb;
        } else {
            plds[rla][lane] = bf16_rne(da * acca[0]);
            plds[rla + 1][lane] = bf16_rne(db * accb[0]);
        }
    }
    __syncthreads();

    // ---- phase 2: MFMA (layout verified R9/R11) ----
    int quad = lane >> 4;
    int l16 = lane & 15;
    bf16x8 afr[KB];
#pragma unroll
    for (int kb = 0; kb < KB; ++kb)
        afr[kb] = *(const bf16x8*)(const void*)&plds[l16][kb * 32 + quad * 8];
#pragma unroll
    for (int fi = 0; fi < FPW; ++fi) {
        int f0 = (wave * FPW + fi) * 16;
        const unsigned short* wrow = Wt + (long)(f0 + l16) * K + quad * 8;
        f32x4 acc4 = {0.f, 0.f, 0.f, 0.f};
#pragma unroll
        for (int kb = 0; kb < KB; ++kb) {
            bf16x8 bb = *(const bf16x8*)(const void*)(wrow + kb * 32);
            acc4 = __builtin_amdgcn_mfma_f32_16x16x32_bf16(afr[kb], bb, acc4, 0, 0, 0);
        }
        float bias = b[f0 + l16];
#pragma unroll
        for (int r = 0; r < 4; ++r) {
            int m = m0 + quad * 4 + r;
            float val = fmaxf(acc4[r] + bias, 0.0f);
            if (PRESCALE) val *= dinv[m];
            out[(long)m * F + f0 + l16] = bf16_rne(val);
        }
    }
}

// ---- pooling over bf16 h3: 64 nodes/block, register acc, flush on change ---
#define POOL_CHUNK 64
__global__ __launch_bounds__(256) void k_pool(
        const unsigned short* __restrict__ h, const int* __restrict__ batch,
        float* __restrict__ psum, int N) {
    int tid = threadIdx.x;  // feature
    int n0 = blockIdx.x * POOL_CHUNK;
    int n1 = n0 + POOL_CHUNK;
    if (n1 > N) n1 = N;
    int gcur = batch[n0];  // sorted -> uniform scalar
    float racc = 0.0f;
    for (int n = n0; n < n1; ++n) {
        int g = batch[n];
        if (g != gcur) {
            atomicAdd(&psum[gcur * 256 + tid], racc);
            racc = 0.0f;
            gcur = g;
        }
        racc += bfl(h[(long)n * 256 + tid]);
    }
    atomicAdd(&psum[gcur * 256 + tid], racc);
}

// ---- final FC --------------------------------------------------------------
__global__ void k_fc(const float* __restrict__ psum, const float* __restrict__ pcnt,
                     const float* __restrict__ Wfc, const float* __restrict__ bfc,
                     float* __restrict__ out) {
    int tid = blockIdx.x * blockDim.x + threadIdx.x;
    if (tid >= NUM_GRAPHS * NUM_CLASSES) return;
    int g = tid / NUM_CLASSES;
    int c = tid % NUM_CLASSES;
    float s = 0.0f;
#pragma unroll 8
    for (int k = 0; k < 256; ++k) s = fmaf(psum[g * 256 + k], Wfc[k * NUM_CLASSES + c], s);
    float cnt = pcnt[g];
    cnt = cnt > 1.0f ? cnt : 1.0f;
    out[tid] = s / cnt + bfc[c];
}

extern "C" void kernel_launch(void* const* d_in, const int* in_sizes, int n_in,
                              void* d_out, int out_size, void* d_ws, size_t ws_size,
                              hipStream_t stream) {
    const float* x     = (const float*)d_in[0];
    const int*   ei    = (const int*)d_in[1];
    const int*   batch = (const int*)d_in[2];
    const float* W1    = (const float*)d_in[3];
    const float* b1    = (const float*)d_in[4];
    const float* W2    = (const float*)d_in[5];
    const float* b2    = (const float*)d_in[6];
    const float* W3    = (const float*)d_in[7];
    const float* b3    = (const float*)d_in[8];
    const float* Wfc   = (const float*)d_in[9];
    const float* bfc   = (const float*)d_in[10];
    float* out = (float*)d_out;

    const int* row = ei;            // src
    const int* col = ei + N_EDGES;  // dst

    // workspace layout (~85 MB), bf16 arrays 16B-aligned
    float*  bufA = (float*)d_ws;                         // N*256 f32 (H3 bf16 lives here)
    float*  xs   = bufA + (size_t)N_NODES * 256;         // N*3 f32 (pre-scaled x)
    float*  dinv = xs + (size_t)N_NODES * 3;             // N
    float*  psum = dinv + N_NODES;                       // 16*256
    float*  pcnt = psum + NUM_GRAPHS * 256;              // 16
    unsigned short* X   = (unsigned short*)(pcnt + NUM_GRAPHS);  // N*128 bf16 (h1')
    unsigned short* Y   = X + (size_t)N_NODES * 128;             // N*128 bf16 (h2')
    unsigned short* Wt2 = Y + (size_t)N_NODES * 128;             // 128*64
    unsigned short* Wt3 = Wt2 + 128 * 64;                        // 256*128
    unsigned short* H3  = (unsigned short*)bufA;                 // N*256 bf16
    int* degi   = (int*)(Wt3 + 256 * 128);               // N
    int* rowptr = degi + N_NODES;                        // N+1
    int* csrsrc = rowptr + N_NODES + 1;                  // E
    int* pos    = csrsrc + N_EDGES;                      // E
    int* bsum   = pos + N_EDGES;                         // SCAN_BLOCKS

    hipMemsetAsync(degi, 0, N_NODES * sizeof(int), stream);
    hipMemsetAsync(psum, 0, (NUM_GRAPHS * 256 + NUM_GRAPHS) * sizeof(float), stream);

    // ---- CSR build + norms + pre-scaled x + weight casts ----
    k_deg<<<nblk(N_EDGES), 256, 0, stream>>>(col, degi, pos, N_EDGES);
    k_scan1<<<SCAN_BLOCKS, 256, 0, stream>>>(degi, rowptr, bsum, batch, pcnt, N_NODES);
    k_scan3<<<SCAN_BLOCKS, 256, 0, stream>>>(rowptr, bsum, degi, dinv, x, xs,
                                             W2, W3, Wt2, Wt3, N_NODES);
    k_fill<<<nblk(N_EDGES), 256, 0, stream>>>(row, col, rowptr, pos, csrsrc, N_EDGES);

    // ---- layer 1 (fused prop+linear): X = h1' = d*relu((A~x)W1+b1), bf16 ---
    k_layer1<<<nblk(N_NODES), 256, 0, stream>>>(xs, dinv, rowptr, csrsrc, W1, b1, X, N_NODES);

    int mtiles = N_NODES / 16;  // 3125, exact

    // ---- layer 2 fused: Y = h2' = d*relu((A~-apply X) W2 + b2) -------------
    k_fused<64, 128, true><<<mtiles, 256, 0, stream>>>(X, dinv, rowptr, csrsrc,
                                                       Wt2, b2, Y, N_NODES);

    // ---- layer 3 fused: H3 = h3 = relu((A~-apply Y) W3 + b3) (unscaled) ----
    k_fused<128, 256, false><<<mtiles, 256, 0, stream>>>(Y, dinv, rowptr, csrsrc,
                                                         Wt3, b3, H3, N_NODES);

    // ---- global mean pool + FC ----
    int pool_blocks = (N_NODES + POOL_CHUNK - 1) / POOL_CHUNK;
    k_pool<<<pool_blocks, 256, 0, stream>>>(H3, batch, psum, N_NODES);
    k_fc<<<nblk(NUM_GRAPHS * NUM_CLASSES), 256, 0, stream>>>(psum, pcnt, Wfc, bfc, out);
}

// Round 16
// 276.630 us; speedup vs baseline: 1.0579x; 1.0355x over previous
//
#include <hip/hip_runtime.h>

#define N_NODES 50000
#define N_EDGES 800000
#define NUM_GRAPHS 16
#define NUM_CLASSES 247
#define SCAN_BLOCKS ((N_NODES + 255) / 256)  // 196

typedef __attribute__((ext_vector_type(8))) short bf16x8;
typedef __attribute__((ext_vector_type(4))) float f32x4;

static inline int nblk(long n) { return (int)((n + 255) / 256); }

__device__ __forceinline__ float bfl(unsigned short u) {
    return __uint_as_float((unsigned)u << 16);
}
__device__ __forceinline__ unsigned short bf16_rne(float f) {
    unsigned u = __float_as_uint(f);
    u += 0x7FFF + ((u >> 16) & 1);
    return (unsigned short)(u >> 16);
}

// ---- degree histogram into 8 XCD-local copies; returns rank within copy ----
// c8 = (e>>8)&7 == blockIdx&7 for 256-thr blocks: one copy per XCD-ish slice,
// atomics resolve in the local L2 instead of the device coherence point.
// Correctness does NOT depend on the real block->XCD mapping.
__global__ void k_deg(const int* __restrict__ col, int* __restrict__ degc,
                      int* __restrict__ pos, int E) {
    int e = blockIdx.x * blockDim.x + threadIdx.x;
    if (e >= E) return;
    int c8 = (e >> 8) & 7;
    pos[e] = atomicAdd(&degc[c8 * N_NODES + col[e]], 1);
}

// ---- scan phase 1: per-block exclusive scan of total degree + batch hist ---
__global__ __launch_bounds__(256) void k_scan1(const int* __restrict__ degc,
                                               int* __restrict__ rowptr,
                                               int* __restrict__ bsum,
                                               const int* __restrict__ batch,
                                               float* __restrict__ pcnt, int N) {
    __shared__ int buf[256];
    __shared__ int hist[NUM_GRAPHS];
    int t = threadIdx.x;
    if (t < NUM_GRAPHS) hist[t] = 0;
    int i = blockIdx.x * 256 + t;
    int v = 0;
    if (i < N) {
#pragma unroll
        for (int c = 0; c < 8; ++c) v += degc[c * N_NODES + i];
        atomicAdd(&hist[batch[i]], 1);
    }
    buf[t] = v;
    __syncthreads();
#pragma unroll
    for (int off = 1; off < 256; off <<= 1) {
        int tmp = (t >= off) ? buf[t - off] : 0;
        __syncthreads();
        if (t >= off) buf[t] += tmp;
        __syncthreads();
    }
    if (i < N) rowptr[i] = buf[t] - v;  // exclusive within block
    if (t == 255) bsum[blockIdx.x] = buf[255];
    if (t < NUM_GRAPHS && hist[t] > 0) atomicAdd(&pcnt[t], (float)hist[t]);
}

// ---- scan phase 2 (folded): block-offset + per-copy bases + dinv + xs + Wt -
__global__ __launch_bounds__(256) void k_scan3(int* __restrict__ rowptr,
                                               const int* __restrict__ bsum,
                                               const int* __restrict__ degc,
                                               int* __restrict__ base,
                                               float* __restrict__ dinv,
                                               const float* __restrict__ x,
                                               float* __restrict__ xs,
                                               const float* __restrict__ W2,
                                               const float* __restrict__ W3,
                                               unsigned short* __restrict__ Wt2,
                                               unsigned short* __restrict__ Wt3,
                                               int N) {
    __shared__ int red[256];
    int t = threadIdx.x;
    int b = blockIdx.x;
    red[t] = (t < b) ? bsum[t] : 0;  // b <= 195 < 256
    __syncthreads();
#pragma unroll
    for (int off = 128; off > 0; off >>= 1) {
        if (t < off) red[t] += red[t + off];
        __syncthreads();
    }
    int boff = red[0];
    int i = b * 256 + t;
    if (i < N) {
        int rp = rowptr[i] + boff;
        rowptr[i] = rp;
        int run = rp, tot = 0;
#pragma unroll
        for (int c = 0; c < 8; ++c) {
            int d = degc[c * N_NODES + i];
            base[c * N_NODES + i] = run;
            run += d;
            tot += d;
        }
        float dv = rsqrtf((float)tot + 1.0f);  // +1 = self loop
        dinv[i] = dv;
        xs[i * 3 + 0] = dv * x[i * 3 + 0];
        xs[i * 3 + 1] = dv * x[i * 3 + 1];
        xs[i * 3 + 2] = dv * x[i * 3 + 2];
    }
    if (i == 0) rowptr[N] = N_EDGES;
    // folded weight cast+transpose (40960 items over 50176 threads)
    if (i < 64 * 128) {                       // Wt2: [f=128][k=64]
        int f = i / 64, k = i % 64;
        Wt2[i] = bf16_rne(W2[k * 128 + f]);
    } else if (i < 64 * 128 + 128 * 256) {    // Wt3: [f=256][k=128]
        int j = i - 64 * 128;
        int f = j / 128, k = j % 128;
        Wt3[j] = bf16_rne(W3[k * 256 + f]);
    }
}

// ---- CSR fill: no atomic; slot = base[copy][dst] + rank-within-copy --------
__global__ void k_fill(const int* __restrict__ row, const int* __restrict__ col,
                       const int* __restrict__ base, const int* __restrict__ pos,
                       int* __restrict__ csr_src, int E) {
    int e = blockIdx.x * blockDim.x + threadIdx.x;
    if (e >= E) return;
    int c8 = (e >> 8) & 7;
    csr_src[base[c8 * N_NODES + col[e]] + pos[e]] = row[e];
}

// ---- fused layer 1: p1 = dv*(xs[v]+Σxs[r]); h1' = dv*relu(p1 W1 + b1) ------
// 4-edge unroll: 12 independent gather-dwords in flight per thread.
__global__ void k_layer1(const float* __restrict__ xs, const float* __restrict__ dinv,
                         const int* __restrict__ rowptr, const int* __restrict__ csr_src,
                         const float* __restrict__ W1, const float* __restrict__ b1,
                         unsigned short* __restrict__ out, int N) {
    int v = blockIdx.x * blockDim.x + threadIdx.x;
    if (v >= N) return;
    float a0 = xs[v * 3 + 0];
    float a1 = xs[v * 3 + 1];
    float a2 = xs[v * 3 + 2];
    int j = rowptr[v];
    int j1 = rowptr[v + 1];
    for (; j + 4 <= j1; j += 4) {
        int r0 = csr_src[j + 0], r1 = csr_src[j + 1];
        int r2 = csr_src[j + 2], r3 = csr_src[j + 3];
        float x00 = xs[r0 * 3 + 0], x01 = xs[r0 * 3 + 1], x02 = xs[r0 * 3 + 2];
        float x10 = xs[r1 * 3 + 0], x11 = xs[r1 * 3 + 1], x12 = xs[r1 * 3 + 2];
        float x20 = xs[r2 * 3 + 0], x21 = xs[r2 * 3 + 1], x22 = xs[r2 * 3 + 2];
        float x30 = xs[r3 * 3 + 0], x31 = xs[r3 * 3 + 1], x32 = xs[r3 * 3 + 2];
        a0 += x00; a1 += x01; a2 += x02;
        a0 += x10; a1 += x11; a2 += x12;
        a0 += x20; a1 += x21; a2 += x22;
        a0 += x30; a1 += x31; a2 += x32;
    }
    for (; j < j1; ++j) {
        int r = csr_src[j];
        a0 += xs[r * 3 + 0];
        a1 += xs[r * 3 + 1];
        a2 += xs[r * 3 + 2];
    }
    float dv = dinv[v];
    float p0 = dv * a0, p1 = dv * a1, p2 = dv * a2;
    unsigned short* ov = out + (long)v * 64;
#pragma unroll
    for (int f = 0; f < 64; f += 2) {
        float s0 = fmaf(p0, W1[f],     fmaf(p1, W1[64 + f],     fmaf(p2, W1[128 + f],     b1[f])));
        float s1 = fmaf(p0, W1[f + 1], fmaf(p1, W1[64 + f + 1], fmaf(p2, W1[128 + f + 1], b1[f + 1])));
        s0 = fmaxf(s0, 0.0f) * dv;  // pre-scale for next prop
        s1 = fmaxf(s1, 0.0f) * dv;
        unsigned pk = (unsigned)bf16_rne(s0) | ((unsigned)bf16_rne(s1) << 16);
        *(unsigned*)(ov + f) = pk;
    }
}

// ---- FUSED prop + MFMA GEMM per 16-row m-tile, 2-ROW INTERLEAVED GATHER ----
// R13/R14/R15 established: gather is L2-fill bound (~2 TB/s, FETCH = cold
// ideal); this structure (16 outstanding loads, zero extra VALU) is the best
// of three variants. Phase 2 = verified R9/R11 MFMA layout.
template <int K, int F, bool PRESCALE>
__global__ __launch_bounds__(256) void k_fused(
        const unsigned short* __restrict__ h, const float* __restrict__ dinv,
        const int* __restrict__ rowptr, const int* __restrict__ csr_src,
        const unsigned short* __restrict__ Wt, const float* __restrict__ b,
        unsigned short* __restrict__ out, int N) {
    constexpr int NF = F / 16;    // f-tiles: 8 (F=128) / 16 (F=256)
    constexpr int FPW = NF / 4;   // f-tiles per wave: 2 / 4
    constexpr int KB = K / 32;    // k-blocks: 2 / 4
    constexpr int KL = K / 64;    // features per lane in prop: 1 / 2
    constexpr int PADK = K + 8;
    __shared__ unsigned short plds[16][PADK];
    int wave = threadIdx.x >> 6;
    int lane = threadIdx.x & 63;
    int m0 = blockIdx.x * 16;

    // ---- phase 1: propagation into LDS, rows processed in pairs ----
    for (int pr = 0; pr < 2; ++pr) {
        int va = m0 + wave * 4 + pr * 2;
        int vb = va + 1;
        float acca[KL], accb[KL];
        const unsigned short* hva = h + (long)va * K + lane * KL;
        const unsigned short* hvb = h + (long)vb * K + lane * KL;
        if (KL == 2) {
            unsigned ua = *(const unsigned*)hva;
            unsigned ub = *(const unsigned*)hvb;
            acca[0] = __uint_as_float(ua << 16);
            acca[1] = __uint_as_float(ua & 0xFFFF0000u);
            accb[0] = __uint_as_float(ub << 16);
            accb[1] = __uint_as_float(ub & 0xFFFF0000u);
        } else {
            acca[0] = bfl(hva[0]);
            accb[0] = bfl(hvb[0]);
        }
        int ja  = __builtin_amdgcn_readfirstlane(rowptr[va]);
        int j1a = __builtin_amdgcn_readfirstlane(rowptr[va + 1]);
        int jb  = j1a;  // rowptr[vb] == rowptr[va+1]
        int j1b = __builtin_amdgcn_readfirstlane(rowptr[vb + 1]);
        // paired main loop: 2 x 8 independent loads in flight
        while (ja + 8 <= j1a && jb + 8 <= j1b) {
            int ra[8], rb[8];
#pragma unroll
            for (int u = 0; u < 8; ++u) ra[u] = csr_src[ja + u];
#pragma unroll
            for (int u = 0; u < 8; ++u) rb[u] = csr_src[jb + u];
            if (KL == 2) {
                unsigned ta[8], tb[8];
#pragma unroll
                for (int u = 0; u < 8; ++u)
                    ta[u] = *(const unsigned*)(h + (long)ra[u] * K + lane * 2);
#pragma unroll
                for (int u = 0; u < 8; ++u)
                    tb[u] = *(const unsigned*)(h + (long)rb[u] * K + lane * 2);
#pragma unroll
                for (int u = 0; u < 8; ++u) {
                    acca[0] += __uint_as_float(ta[u] << 16);
                    acca[1] += __uint_as_float(ta[u] & 0xFFFF0000u);
                }
#pragma unroll
                for (int u = 0; u < 8; ++u) {
                    accb[0] += __uint_as_float(tb[u] << 16);
                    accb[1] += __uint_as_float(tb[u] & 0xFFFF0000u);
                }
            } else {
                unsigned short ta[8], tb[8];
#pragma unroll
                for (int u = 0; u < 8; ++u) ta[u] = h[(long)ra[u] * K + lane];
#pragma unroll
                for (int u = 0; u < 8; ++u) tb[u] = h[(long)rb[u] * K + lane];
#pragma unroll
                for (int u = 0; u < 8; ++u) acca[0] += bfl(ta[u]);
#pragma unroll
                for (int u = 0; u < 8; ++u) accb[0] += bfl(tb[u]);
            }
            ja += 8;
            jb += 8;
        }
        // drain row a
        for (; ja + 8 <= j1a; ja += 8) {
            int r[8];
#pragma unroll
            for (int u = 0; u < 8; ++u) r[u] = csr_src[ja + u];
            if (KL == 2) {
                unsigned tv[8];
#pragma unroll
                for (int u = 0; u < 8; ++u)
                    tv[u] = *(const unsigned*)(h + (long)r[u] * K + lane * 2);
#pragma unroll
                for (int u = 0; u < 8; ++u) {
                    acca[0] += __uint_as_float(tv[u] << 16);
                    acca[1] += __uint_as_float(tv[u] & 0xFFFF0000u);
                }
            } else {
                unsigned short tv[8];
#pragma unroll
                for (int u = 0; u < 8; ++u) tv[u] = h[(long)r[u] * K + lane];
#pragma unroll
                for (int u = 0; u < 8; ++u) acca[0] += bfl(tv[u]);
            }
        }
        for (; ja < j1a; ++ja) {
            int r = csr_src[ja];
            if (KL == 2) {
                unsigned u = *(const unsigned*)(h + (long)r * K + lane * 2);
                acca[0] += __uint_as_float(u << 16);
                acca[1] += __uint_as_float(u & 0xFFFF0000u);
            } else {
                acca[0] += bfl(h[(long)r * K + lane]);
            }
        }
        // drain row b
        for (; jb + 8 <= j1b; jb += 8) {
            int r[8];
#pragma unroll
            for (int u = 0; u < 8; ++u) r[u] = csr_src[jb + u];
            if (KL == 2) {
                unsigned tv[8];
#pragma unroll
                for (int u = 0; u < 8; ++u)
                    tv[u] = *(const unsigned*)(h + (long)r[u] * K + lane * 2);
#pragma unroll
                for (int u = 0; u < 8; ++u) {
                    accb[0] += __uint_as_float(tv[u] << 16);
                    accb[1] += __uint_as_float(tv[u] & 0xFFFF0000u);
                }
            } else {
                unsigned short tv[8];
#pragma unroll
                for (int u = 0; u < 8; ++u) tv[u] = h[(long)r[u] * K + lane];
#pragma unroll
                for (int u = 0; u < 8; ++u) accb[0] += bfl(tv[u]);
            }
        }
        for (; jb < j1b; ++jb) {
            int r = csr_src[jb];
            if (KL == 2) {
                unsigned u = *(const unsigned*)(h + (long)r * K + lane * 2);
                accb[0] += __uint_as_float(u << 16);
                accb[1] += __uint_as_float(u & 0xFFFF0000u);
            } else {
                accb[0] += bfl(h[(long)r * K + lane]);
            }
        }
        float da = dinv[va];
        float db = dinv[vb];
        int rla = wave * 4 + pr * 2;
        if (KL == 2) {
            unsigned pa = (unsigned)bf16_rne(da * acca[0]) | ((unsigned)bf16_rne(da * acca[1]) << 16);
            unsigned pb = (unsigned)bf16_rne(db * accb[0]) | ((unsigned)bf16_rne(db * accb[1]) << 16);
            *(unsigned*)&plds[rla][lane * 2] = pa;
            *(unsigned*)&plds[rla + 1][lane * 2] = pb;
        } else {
            plds[rla][lane] = bf16_rne(da * acca[0]);
            plds[rla + 1][lane] = bf16_rne(db * accb[0]);
        }
    }
    __syncthreads();

    // ---- phase 2: MFMA (layout verified R9/R11) ----
    int quad = lane >> 4;
    int l16 = lane & 15;
    bf16x8 afr[KB];
#pragma unroll
    for (int kb = 0; kb < KB; ++kb)
        afr[kb] = *(const bf16x8*)(const void*)&plds[l16][kb * 32 + quad * 8];
#pragma unroll
    for (int fi = 0; fi < FPW; ++fi) {
        int f0 = (wave * FPW + fi) * 16;
        const unsigned short* wrow = Wt + (long)(f0 + l16) * K + quad * 8;
        f32x4 acc4 = {0.f, 0.f, 0.f, 0.f};
#pragma unroll
        for (int kb = 0; kb < KB; ++kb) {
            bf16x8 bb = *(const bf16x8*)(const void*)(wrow + kb * 32);
            acc4 = __builtin_amdgcn_mfma_f32_16x16x32_bf16(afr[kb], bb, acc4, 0, 0, 0);
        }
        float bias = b[f0 + l16];
#pragma unroll
        for (int r = 0; r < 4; ++r) {
            int m = m0 + quad * 4 + r;
            float val = fmaxf(acc4[r] + bias, 0.0f);
            if (PRESCALE) val *= dinv[m];
            out[(long)m * F + f0 + l16] = bf16_rne(val);
        }
    }
}

// ---- pooling over bf16 h3: 64 nodes/block, register acc, flush on change ---
#define POOL_CHUNK 64
__global__ __launch_bounds__(256) void k_pool(
        const unsigned short* __restrict__ h, const int* __restrict__ batch,
        float* __restrict__ psum, int N) {
    int tid = threadIdx.x;  // feature
    int n0 = blockIdx.x * POOL_CHUNK;
    int n1 = n0 + POOL_CHUNK;
    if (n1 > N) n1 = N;
    int gcur = batch[n0];  // sorted -> uniform scalar
    float racc = 0.0f;
    for (int n = n0; n < n1; ++n) {
        int g = batch[n];
        if (g != gcur) {
            atomicAdd(&psum[gcur * 256 + tid], racc);
            racc = 0.0f;
            gcur = g;
        }
        racc += bfl(h[(long)n * 256 + tid]);
    }
    atomicAdd(&psum[gcur * 256 + tid], racc);
}

// ---- final FC --------------------------------------------------------------
__global__ void k_fc(const float* __restrict__ psum, const float* __restrict__ pcnt,
                     const float* __restrict__ Wfc, const float* __restrict__ bfc,
                     float* __restrict__ out) {
    int tid = blockIdx.x * blockDim.x + threadIdx.x;
    if (tid >= NUM_GRAPHS * NUM_CLASSES) return;
    int g = tid / NUM_CLASSES;
    int c = tid % NUM_CLASSES;
    float s = 0.0f;
#pragma unroll 8
    for (int k = 0; k < 256; ++k) s = fmaf(psum[g * 256 + k], Wfc[k * NUM_CLASSES + c], s);
    float cnt = pcnt[g];
    cnt = cnt > 1.0f ? cnt : 1.0f;
    out[tid] = s / cnt + bfc[c];
}

extern "C" void kernel_launch(void* const* d_in, const int* in_sizes, int n_in,
                              void* d_out, int out_size, void* d_ws, size_t ws_size,
                              hipStream_t stream) {
    const float* x     = (const float*)d_in[0];
    const int*   ei    = (const int*)d_in[1];
    const int*   batch = (const int*)d_in[2];
    const float* W1    = (const float*)d_in[3];
    const float* b1    = (const float*)d_in[4];
    const float* W2    = (const float*)d_in[5];
    const float* b2    = (const float*)d_in[6];
    const float* W3    = (const float*)d_in[7];
    const float* b3    = (const float*)d_in[8];
    const float* Wfc   = (const float*)d_in[9];
    const float* bfc   = (const float*)d_in[10];
    float* out = (float*)d_out;

    const int* row = ei;            // src
    const int* col = ei + N_EDGES;  // dst

    // workspace layout (~88 MB), bf16 arrays 16B-aligned
    float*  bufA = (float*)d_ws;                         // N*256 f32 (H3 bf16 lives here)
    float*  xs   = bufA + (size_t)N_NODES * 256;         // N*3 f32 (pre-scaled x)
    float*  dinv = xs + (size_t)N_NODES * 3;             // N
    float*  psum = dinv + N_NODES;                       // 16*256
    float*  pcnt = psum + NUM_GRAPHS * 256;              // 16
    unsigned short* X   = (unsigned short*)(pcnt + NUM_GRAPHS);  // N*128 bf16 (h1')
    unsigned short* Y   = X + (size_t)N_NODES * 128;             // N*128 bf16 (h2')
    unsigned short* Wt2 = Y + (size_t)N_NODES * 128;             // 128*64
    unsigned short* Wt3 = Wt2 + 128 * 64;                        // 256*128
    unsigned short* H3  = (unsigned short*)bufA;                 // N*256 bf16
    int* degc   = (int*)(Wt3 + 256 * 128);               // 8*N (XCD-local copies)
    int* base   = degc + 8 * N_NODES;                    // 8*N (per-copy slot bases)
    int* rowptr = base + 8 * N_NODES;                    // N+1
    int* csrsrc = rowptr + N_NODES + 1;                  // E
    int* pos    = csrsrc + N_EDGES;                      // E
    int* bsum   = pos + N_EDGES;                         // SCAN_BLOCKS

    hipMemsetAsync(degc, 0, 8 * N_NODES * sizeof(int), stream);
    hipMemsetAsync(psum, 0, (NUM_GRAPHS * 256 + NUM_GRAPHS) * sizeof(float), stream);

    // ---- CSR build + norms + pre-scaled x + weight casts ----
    k_deg<<<nblk(N_EDGES), 256, 0, stream>>>(col, degc, pos, N_EDGES);
    k_scan1<<<SCAN_BLOCKS, 256, 0, stream>>>(degc, rowptr, bsum, batch, pcnt, N_NODES);
    k_scan3<<<SCAN_BLOCKS, 256, 0, stream>>>(rowptr, bsum, degc, base, dinv, x, xs,
                                             W2, W3, Wt2, Wt3, N_NODES);
    k_fill<<<nblk(N_EDGES), 256, 0, stream>>>(row, col, base, pos, csrsrc, N_EDGES);

    // ---- layer 1 (fused prop+linear): X = h1' = d*relu((A~x)W1+b1), bf16 ---
    k_layer1<<<nblk(N_NODES), 256, 0, stream>>>(xs, dinv, rowptr, csrsrc, W1, b1, X, N_NODES);

    int mtiles = N_NODES / 16;  // 3125, exact

    // ---- layer 2 fused: Y = h2' = d*relu((A~-apply X) W2 + b2) -------------
    k_fused<64, 128, true><<<mtiles, 256, 0, stream>>>(X, dinv, rowptr, csrsrc,
                                                       Wt2, b2, Y, N_NODES);

    // ---- layer 3 fused: H3 = h3 = relu((A~-apply Y) W3 + b3) (unscaled) ----
    k_fused<128, 256, false><<<mtiles, 256, 0, stream>>>(Y, dinv, rowptr, csrsrc,
                                                         Wt3, b3, H3, N_NODES);

    // ---- global mean pool + FC ----
    int pool_blocks = (N_NODES + POOL_CHUNK - 1) / POOL_CHUNK;
    k_pool<<<pool_blocks, 256, 0, stream>>>(H3, batch, psum, N_NODES);
    k_fc<<<nblk(NUM_GRAPHS * NUM_CLASSES), 256, 0, stream>>>(psum, pcnt, Wfc, bfc, out);
}